// Round 13
// baseline (407.472 us; speedup 1.0000x reference)
//
#include <hip/hip_runtime.h>

#define D_IN  128
#define D_HID 64
#define D_OUT 40

static __device__ __forceinline__ unsigned short f2bf(float f) {
    unsigned int u = __float_as_uint(f);
    unsigned int r = (u + 0x7fffu + ((u >> 16) & 1u)) >> 16;   // RNE
    return (unsigned short)r;
}
static __device__ __forceinline__ float bflo(unsigned int u) {
    return __uint_as_float(u << 16);
}
static __device__ __forceinline__ float bfhi(unsigned int u) {
    return __uint_as_float(u & 0xffff0000u);
}

// ---- FUSED: degree/rank atomics (blocks < DB) + LDS-FREE gemm1 (rest) ----
// deg role: fabric-latency-bound, idle VALU. gemm1 role: W1 (32 KB) is
// L1-resident; x row reads are 16-lane broadcasts; W reads tile 256 B
// contiguous per wave. Zero LDS -> deg occupancy not throttled (r12 lesson).
// h1s is UNSCALED bf16 (dinv not computed yet); gather applies dinv[src].
__global__ __launch_bounds__(256) void k_deg_g1(const int* __restrict__ dst,
                                                unsigned int* __restrict__ cnt,
                                                unsigned int* __restrict__ rank, int E, int DB,
                                                const float* __restrict__ x,
                                                const float* __restrict__ W1,
                                                unsigned short* __restrict__ h1s, int N) {
    if ((int)blockIdx.x < DB) {              // ---- deg role ----
        int e = blockIdx.x * 256 + threadIdx.x;
        if (e < E) rank[e] = atomicAdd(&cnt[dst[e]], 1u);
        return;
    }
    // ---- gemm1 role (no LDS) ----
    const int tid = threadIdx.x;
    const int r   = tid >> 4;                // 0..15
    const int c4  = (tid & 15) * 4;          // 0,4,..,60
    const int row = ((int)blockIdx.x - DB) * 16 + r;
    if (row >= N) return;
    const float* xrow = x + (size_t)row * D_IN;
    float a0 = 0, a1 = 0, a2 = 0, a3 = 0;
#pragma unroll 2
    for (int k0 = 0; k0 < D_IN; k0 += 4) {
        float4 xv = *(const float4*)&xrow[k0];               // 16-lane broadcast
        float4 w0 = *(const float4*)&W1[(k0 + 0) * D_HID + c4];
        float4 w1 = *(const float4*)&W1[(k0 + 1) * D_HID + c4];
        float4 w2 = *(const float4*)&W1[(k0 + 2) * D_HID + c4];
        float4 w3 = *(const float4*)&W1[(k0 + 3) * D_HID + c4];
        a0 = fmaf(xv.x, w0.x, a0); a1 = fmaf(xv.x, w0.y, a1);
        a2 = fmaf(xv.x, w0.z, a2); a3 = fmaf(xv.x, w0.w, a3);
        a0 = fmaf(xv.y, w1.x, a0); a1 = fmaf(xv.y, w1.y, a1);
        a2 = fmaf(xv.y, w1.z, a2); a3 = fmaf(xv.y, w1.w, a3);
        a0 = fmaf(xv.z, w2.x, a0); a1 = fmaf(xv.z, w2.y, a1);
        a2 = fmaf(xv.z, w2.z, a2); a3 = fmaf(xv.z, w2.w, a3);
        a0 = fmaf(xv.w, w3.x, a0); a1 = fmaf(xv.w, w3.y, a1);
        a2 = fmaf(xv.w, w3.z, a2); a3 = fmaf(xv.w, w3.w, a3);
    }
    uint2 o;
    o.x = (unsigned)f2bf(a0) | ((unsigned)f2bf(a1) << 16);
    o.y = (unsigned)f2bf(a2) | ((unsigned)f2bf(a3) << 16);
    *(uint2*)&h1s[(size_t)row * D_HID + c4] = o;
}

// ---- scan1 + fused dinv = rsqrt(deg+1) ----
__global__ __launch_bounds__(256) void k_scan1(const unsigned int* __restrict__ deg,
                                               unsigned int* __restrict__ off,
                                               unsigned int* __restrict__ bsum,
                                               float* __restrict__ dinv, int N) {
    __shared__ unsigned int s[256];
    const int tid = threadIdx.x;
    const int i = blockIdx.x * 256 + tid;
    unsigned int v = (i < N) ? deg[i] : 0u;
    if (i < N) dinv[i] = rsqrtf((float)(v + 1u));
    s[tid] = v;
    __syncthreads();
    for (int d = 1; d < 256; d <<= 1) {
        unsigned int t = (tid >= d) ? s[tid - d] : 0u;
        __syncthreads();
        s[tid] += t;
        __syncthreads();
    }
    if (i < N) off[i] = s[tid] - v;              // exclusive
    if (tid == 255) bsum[blockIdx.x] = s[tid];   // block total
}

__global__ __launch_bounds__(512) void k_scan2(unsigned int* __restrict__ bsum, int NB) {
    __shared__ unsigned int s[512];
    const int tid = threadIdx.x;
    unsigned int v = (tid < NB) ? bsum[tid] : 0u;
    s[tid] = v;
    __syncthreads();
    for (int d = 1; d < 512; d <<= 1) {
        unsigned int t = (tid >= d) ? s[tid - d] : 0u;
        __syncthreads();
        s[tid] += t;
        __syncthreads();
    }
    if (tid < NB) bsum[tid] = s[tid] - v;        // exclusive over block sums
}

__global__ __launch_bounds__(256) void k_scan3(unsigned int* __restrict__ off,
                                               const unsigned int* __restrict__ bsum,
                                               int N, int E) {
    int i = blockIdx.x * 256 + threadIdx.x;
    if (i < N) off[i] += bsum[blockIdx.x];
    if (i == 0) off[N] = (unsigned int)E;
}

// ---- atomic-free counting-sort fill: csr_src[off[dst]+rank] = src ----
__global__ __launch_bounds__(256) void k_fill(const int* __restrict__ src,
                                              const int* __restrict__ dst,
                                              const unsigned int* __restrict__ off,
                                              const unsigned int* __restrict__ rank,
                                              int* __restrict__ csr_src, int E) {
    int e = blockIdx.x * 256 + threadIdx.x;
    if (e >= E) return;
    csr_src[off[dst[e]] + rank[e]] = src[e];
}

// ---- FUSED gather1 + gemm2: per node (2/wave, 32 lanes each):
//   hid = relu(dinv[n]*(Σ_in dinv[s]*h1u[s] + dinv[n]*h1u[n]) + b1)   -> LDS
//   h2s[n] = (hid @ W2) * dinv[n]                                      (bf16)
__global__ __launch_bounds__(256) void k_g1g2(const unsigned int* __restrict__ off,
                                              const int* __restrict__ csr_src,
                                              const unsigned int* __restrict__ h1s, // bf16x2 unscaled
                                              const float* __restrict__ dinv,
                                              const float* __restrict__ b1,
                                              const float* __restrict__ W2,
                                              unsigned short* __restrict__ h2s, int N) {
    __shared__ float w2s[D_HID * D_OUT];     // 10 KB
    __shared__ float hrow[8][D_HID];         // 2 KB
    const int tid = threadIdx.x;
    const float4* W4 = (const float4*)W2;
    float4* w4 = (float4*)w2s;
    for (int i = tid; i < D_HID * D_OUT / 4; i += 256) w4[i] = W4[i];
    __syncthreads();

    const int lane = tid & 63;
    const int half = lane >> 5;
    const int hl   = lane & 31;
    const int slot = (tid >> 6) * 2 + half;   // 0..7
    const int node = blockIdx.x * 8 + slot;
    const bool valid = node < N;

    int start = 0, end = 0;
    float a0 = 0.0f, a1 = 0.0f;
    float dn = 0.0f;
    if (valid) {
        start = (int)off[node];
        end   = (int)off[node + 1];
        dn = dinv[node];
        unsigned int u = h1s[(size_t)node * 32 + hl];
        a0 = dn * bflo(u);
        a1 = dn * bfhi(u);
    }
    for (int base = start; base < end; base += 32) {
        const int nb = min(32, end - base);
        int sv = (base + hl < end) ? csr_src[base + hl] : 0;
        int j = 0;
        for (; j + 3 < nb; j += 4) {
            int s0 = __shfl(sv, j, 32),     s1 = __shfl(sv, j + 1, 32);
            int s2 = __shfl(sv, j + 2, 32), s3 = __shfl(sv, j + 3, 32);
            unsigned int u0 = h1s[(size_t)s0 * 32 + hl]; float d0 = dinv[s0];
            unsigned int u1 = h1s[(size_t)s1 * 32 + hl]; float d1 = dinv[s1];
            unsigned int u2 = h1s[(size_t)s2 * 32 + hl]; float d2 = dinv[s2];
            unsigned int u3 = h1s[(size_t)s3 * 32 + hl]; float d3 = dinv[s3];
            a0 = fmaf(d0, bflo(u0), a0); a1 = fmaf(d0, bfhi(u0), a1);
            a0 = fmaf(d1, bflo(u1), a0); a1 = fmaf(d1, bfhi(u1), a1);
            a0 = fmaf(d2, bflo(u2), a0); a1 = fmaf(d2, bfhi(u2), a1);
            a0 = fmaf(d3, bflo(u3), a0); a1 = fmaf(d3, bfhi(u3), a1);
        }
        for (; j < nb; ++j) {
            int s = __shfl(sv, j, 32);
            unsigned int uu = h1s[(size_t)s * 32 + hl];
            float dd = dinv[s];
            a0 = fmaf(dd, bflo(uu), a0);
            a1 = fmaf(dd, bfhi(uu), a1);
        }
    }
    if (valid) {
        const float2 bb = *(const float2*)&b1[hl * 2];
        float v0 = fmaf(dn, a0, bb.x);
        float v1 = fmaf(dn, a1, bb.y);
        hrow[slot][hl * 2]     = v0 > 0.0f ? v0 : 0.0f;
        hrow[slot][hl * 2 + 1] = v1 > 0.0f ? v1 : 0.0f;
    }
    __syncthreads();
    // gemm2 epilogue: 20 active lanes per node, 2 cols each
    if (valid && hl < 20) {
        const int c2 = hl * 2;
        float s0 = 0.0f, s1 = 0.0f;
#pragma unroll 8
        for (int k = 0; k < D_HID; ++k) {
            float  xv = hrow[slot][k];                    // broadcast
            float2 wv = *(const float2*)&w2s[k * D_OUT + c2];
            s0 = fmaf(xv, wv.x, s0);
            s1 = fmaf(xv, wv.y, s1);
        }
        unsigned int o = (unsigned)f2bf(s0 * dn) | ((unsigned)f2bf(s1 * dn) << 16);
        *(unsigned int*)&h2s[(size_t)node * D_OUT + c2] = o;
    }
}

// ---- gather2: out[n] = dinv[n]*(Σ_in h2s[src] + h2s[n]) + b2   [fp32 out] ----
__global__ __launch_bounds__(256) void k_gather2(const unsigned int* __restrict__ off,
                                                 const int* __restrict__ csr_src,
                                                 const unsigned int* __restrict__ h2s, // bf16x2
                                                 const float* __restrict__ dinv,
                                                 const float* __restrict__ b2,
                                                 float* __restrict__ out, int N) {
    const int gtid = blockIdx.x * 256 + threadIdx.x;
    const int wid2 = gtid >> 6;
    const int lane = threadIdx.x & 63;
    const int half = lane >> 5;
    const int hl   = lane & 31;
    const int node = wid2 * 2 + half;
    if (node >= N) return;
    const int start = (int)off[node];
    const int end   = (int)off[node + 1];
    const bool act = hl < 20;
    float a0 = 0.0f, a1 = 0.0f;
    if (act) {
        unsigned int u = h2s[(size_t)node * 20 + hl];
        a0 = bflo(u); a1 = bfhi(u);
    }
    for (int base = start; base < end; base += 32) {
        const int nb = min(32, end - base);
        int sv = (base + hl < end) ? csr_src[base + hl] : 0;
        int j = 0;
        for (; j + 3 < nb; j += 4) {
            int s0 = __shfl(sv, j, 32),     s1 = __shfl(sv, j + 1, 32);
            int s2 = __shfl(sv, j + 2, 32), s3 = __shfl(sv, j + 3, 32);
            if (act) {
                unsigned int u0 = h2s[(size_t)s0 * 20 + hl];
                unsigned int u1 = h2s[(size_t)s1 * 20 + hl];
                unsigned int u2 = h2s[(size_t)s2 * 20 + hl];
                unsigned int u3 = h2s[(size_t)s3 * 20 + hl];
                a0 += (bflo(u0) + bflo(u1)) + (bflo(u2) + bflo(u3));
                a1 += (bfhi(u0) + bfhi(u1)) + (bfhi(u2) + bfhi(u3));
            }
        }
        for (; j < nb; ++j) {
            int s = __shfl(sv, j, 32);
            if (act) {
                unsigned int uu = h2s[(size_t)s * 20 + hl];
                a0 += bflo(uu);
                a1 += bfhi(uu);
            }
        }
    }
    if (act) {
        const float dv = dinv[node];
        const float2 bb = *(const float2*)&b2[hl * 2];
        float2 o = {fmaf(dv, a0, bb.x), fmaf(dv, a1, bb.y)};
        *(float2*)&out[(size_t)node * D_OUT + hl * 2] = o;
    }
}

extern "C" void kernel_launch(void* const* d_in, const int* in_sizes, int n_in,
                              void* d_out, int out_size, void* d_ws, size_t ws_size,
                              hipStream_t stream) {
    const float* x  = (const float*)d_in[0];
    const int*  eix = (const int*)d_in[1];   // [2, E] int32 per harness contract
    const float* W1 = (const float*)d_in[2];
    const float* b1 = (const float*)d_in[3];
    const float* W2 = (const float*)d_in[4];
    const float* b2 = (const float*)d_in[5];
    float* out = (float*)d_out;

    const int N = in_sizes[0] / D_IN;
    const int E = in_sizes[1] / 2;
    const int* src = eix;
    const int* dst = eix + E;
    const int NB = (N + 255) / 256;   // scan blocks (<=512 required by k_scan2)

    // ws: deg | dinv | offsets(N+1) | bsums(512) | csr_src(E) | h1s(bf16) | h2s(bf16)
    // rank aliases h2s (rank dead after fill; h2s first written in k_g1g2, after fill).
    char* ws = (char*)d_ws;
    size_t off_b = 0;
    auto alloc = [&](size_t bytes) {
        void* p = ws + off_b;
        off_b = (off_b + bytes + 255) & ~(size_t)255;
        return p;
    };
    unsigned int*   deg     = (unsigned int*)alloc((size_t)N * 4);
    float*          dinv    = (float*)alloc((size_t)N * 4);
    unsigned int*   offsets = (unsigned int*)alloc((size_t)(N + 1) * 4);
    unsigned int*   bsums   = (unsigned int*)alloc(512 * 4);
    int*            csr_src = (int*)alloc((size_t)E * 4);
    unsigned short* h1s     = (unsigned short*)alloc((size_t)N * D_HID * 2);
    unsigned short* h2s     = (unsigned short*)alloc((size_t)E >= (size_t)N * D_OUT / 2
                                                     ? (size_t)E * 4 : (size_t)N * D_OUT * 2);
    unsigned int*   rank    = (unsigned int*)h2s;     // alias: rank dead before h2s written

    hipMemsetAsync(deg, 0, (size_t)N * 4, stream);

    const int DB = (E + 255) / 256;                  // deg-role blocks
    const int GB = (N + 15) / 16;                    // gemm1-role blocks

    // fused deg + LDS-free gemm1 (unscaled h1s)
    k_deg_g1<<<DB + GB, 256, 0, stream>>>(dst, deg, rank, E, DB, x, W1, h1s, N);

    // CSR scans + fill
    k_scan1<<<NB, 256, 0, stream>>>(deg, offsets, bsums, dinv, N);
    k_scan2<<<1, 512, 0, stream>>>(bsums, NB);
    k_scan3<<<NB, 256, 0, stream>>>(offsets, bsums, N, E);
    k_fill <<<(E + 255) / 256, 256, 0, stream>>>(src, dst, offsets, rank, csr_src, E);

    // fused gather1 + gemm2 (8 nodes/block), then gather2
    k_g1g2  <<<(N + 7) / 8, 256, 0, stream>>>(offsets, csr_src, (const unsigned int*)h1s,
                                              dinv, b1, W2, h2s, N);
    const int gwaves = (N + 1) / 2;
    const int gblocks = (gwaves + 3) / 4;
    k_gather2<<<gblocks, 256, 0, stream>>>(offsets, csr_src, (const unsigned int*)h2s,
                                           dinv, b2, out, N);
}

// Round 14
// 338.066 us; speedup vs baseline: 1.2053x; 1.2053x over previous
//
#include <hip/hip_runtime.h>

#define D_IN  128
#define D_HID 64
#define D_OUT 40

static __device__ __forceinline__ unsigned short f2bf(float f) {
    unsigned int u = __float_as_uint(f);
    unsigned int r = (u + 0x7fffu + ((u >> 16) & 1u)) >> 16;   // RNE
    return (unsigned short)r;
}
static __device__ __forceinline__ float bflo(unsigned int u) {
    return __uint_as_float(u << 16);
}
static __device__ __forceinline__ float bfhi(unsigned int u) {
    return __uint_as_float(u & 0xffff0000u);
}

// ---- degree count + edge rank; at random-line atomic-fabric roofline ----
// (r12/r13 lesson: do NOT fuse anything into this kernel — both LDS
// reservation and L2-read contention throttle the atomic pipe.)
__global__ __launch_bounds__(256) void k_deg(const int* __restrict__ dst,
                                             unsigned int* __restrict__ cnt,
                                             unsigned int* __restrict__ rank, int E) {
    int e = blockIdx.x * 256 + threadIdx.x;
    if (e < E) rank[e] = atomicAdd(&cnt[dst[e]], 1u);
}

// ---- scan1 + fused dinv = rsqrt(deg+1) ----
__global__ __launch_bounds__(256) void k_scan1(const unsigned int* __restrict__ deg,
                                               unsigned int* __restrict__ off,
                                               unsigned int* __restrict__ bsum,
                                               float* __restrict__ dinv, int N) {
    __shared__ unsigned int s[256];
    const int tid = threadIdx.x;
    const int i = blockIdx.x * 256 + tid;
    unsigned int v = (i < N) ? deg[i] : 0u;
    if (i < N) dinv[i] = rsqrtf((float)(v + 1u));
    s[tid] = v;
    __syncthreads();
    for (int d = 1; d < 256; d <<= 1) {
        unsigned int t = (tid >= d) ? s[tid - d] : 0u;
        __syncthreads();
        s[tid] += t;
        __syncthreads();
    }
    if (i < N) off[i] = s[tid] - v;              // exclusive
    if (tid == 255) bsum[blockIdx.x] = s[tid];   // block total
}

__global__ __launch_bounds__(512) void k_scan2(unsigned int* __restrict__ bsum, int NB) {
    __shared__ unsigned int s[512];
    const int tid = threadIdx.x;
    unsigned int v = (tid < NB) ? bsum[tid] : 0u;
    s[tid] = v;
    __syncthreads();
    for (int d = 1; d < 512; d <<= 1) {
        unsigned int t = (tid >= d) ? s[tid - d] : 0u;
        __syncthreads();
        s[tid] += t;
        __syncthreads();
    }
    if (tid < NB) bsum[tid] = s[tid] - v;        // exclusive over block sums
}

__global__ __launch_bounds__(256) void k_scan3(unsigned int* __restrict__ off,
                                               const unsigned int* __restrict__ bsum,
                                               int N, int E) {
    int i = blockIdx.x * 256 + threadIdx.x;
    if (i < N) off[i] += bsum[blockIdx.x];
    if (i == 0) off[N] = (unsigned int)E;
}

// ---- atomic-free counting-sort fill: csr_src[off[dst]+rank] = src ----
__global__ __launch_bounds__(256) void k_fill(const int* __restrict__ src,
                                              const int* __restrict__ dst,
                                              const unsigned int* __restrict__ off,
                                              const unsigned int* __restrict__ rank,
                                              int* __restrict__ csr_src, int E) {
    int e = blockIdx.x * 256 + threadIdx.x;
    if (e >= E) return;
    csr_src[off[dst[e]] + rank[e]] = src[e];
}

// ---- h1s(bf16, SCALED) = (x @ W1) * dinv[row]; 16 rows/block, LDS version ----
// (r8/r10-measured shape: ~28 µs, no spill.)
__global__ __launch_bounds__(256) void k_gemm1(const float* __restrict__ x,
                                               const float* __restrict__ W1,
                                               const float* __restrict__ dinv,
                                               unsigned short* __restrict__ h1s, int N) {
    __shared__ float w[D_IN * D_HID];        // 32 KB
    __shared__ float xs[16][D_IN + 4];
    const int tid = threadIdx.x;
    const float4* W4 = (const float4*)W1;
    float4* w4 = (float4*)w;
    for (int i = tid; i < D_IN * D_HID / 4; i += 256) w4[i] = W4[i];
    const int row0 = blockIdx.x * 16;
    const float4* X4 = (const float4*)(x + (size_t)row0 * D_IN);
    for (int i = tid; i < 16 * D_IN / 4; i += 256) {
        float4 v = X4[i];
        int r = i >> 5;
        int k = (i & 31) * 4;
        *(float4*)&xs[r][k] = v;
    }
    __syncthreads();
    const int r  = tid >> 4;
    const int c4 = (tid & 15) * 4;
    float a0 = 0, a1 = 0, a2 = 0, a3 = 0;
#pragma unroll 8
    for (int k = 0; k < D_IN; ++k) {
        float  xv = xs[r][k];
        float4 wv = *(const float4*)&w[k * D_HID + c4];
        a0 = fmaf(xv, wv.x, a0);
        a1 = fmaf(xv, wv.y, a1);
        a2 = fmaf(xv, wv.z, a2);
        a3 = fmaf(xv, wv.w, a3);
    }
    const int row = row0 + r;
    if (row < N) {
        float dv = dinv[row];
        uint2 o;
        o.x = (unsigned)f2bf(a0 * dv) | ((unsigned)f2bf(a1 * dv) << 16);
        o.y = (unsigned)f2bf(a2 * dv) | ((unsigned)f2bf(a3 * dv) << 16);
        *(uint2*)&h1s[(size_t)row * D_HID + c4] = o;
    }
}

// ---- FUSED gather1 + gemm2 (scaled h1s: no per-src dinv loads):
//   hid = relu(dinv[n]*(Σ h1s[s] + h1s[n]) + b1)  -> LDS
//   h2s[n] = (hid @ W2) * dinv[n]                   (bf16)
__global__ __launch_bounds__(256) void k_g1g2(const unsigned int* __restrict__ off,
                                              const int* __restrict__ csr_src,
                                              const unsigned int* __restrict__ h1s, // bf16x2 scaled
                                              const float* __restrict__ dinv,
                                              const float* __restrict__ b1,
                                              const float* __restrict__ W2,
                                              unsigned short* __restrict__ h2s, int N) {
    __shared__ float w2s[D_HID * D_OUT];     // 10 KB
    __shared__ float hrow[8][D_HID];         // 2 KB
    const int tid = threadIdx.x;
    const float4* W4 = (const float4*)W2;
    float4* w4 = (float4*)w2s;
    for (int i = tid; i < D_HID * D_OUT / 4; i += 256) w4[i] = W4[i];
    __syncthreads();

    const int lane = tid & 63;
    const int half = lane >> 5;
    const int hl   = lane & 31;
    const int slot = (tid >> 6) * 2 + half;   // 0..7
    const int node = blockIdx.x * 8 + slot;
    const bool valid = node < N;

    int start = 0, end = 0;
    float a0 = 0.0f, a1 = 0.0f, dn = 0.0f;
    if (valid) {
        start = (int)off[node];
        end   = (int)off[node + 1];
        dn = dinv[node];
        unsigned int u = h1s[(size_t)node * 32 + hl];   // self term (scaled)
        a0 = bflo(u);
        a1 = bfhi(u);
    }
    for (int base = start; base < end; base += 32) {
        const int nb = min(32, end - base);
        int sv = (base + hl < end) ? csr_src[base + hl] : 0;
        int j = 0;
        for (; j + 3 < nb; j += 4) {
            int s0 = __shfl(sv, j, 32),     s1 = __shfl(sv, j + 1, 32);
            int s2 = __shfl(sv, j + 2, 32), s3 = __shfl(sv, j + 3, 32);
            unsigned int u0 = h1s[(size_t)s0 * 32 + hl];
            unsigned int u1 = h1s[(size_t)s1 * 32 + hl];
            unsigned int u2 = h1s[(size_t)s2 * 32 + hl];
            unsigned int u3 = h1s[(size_t)s3 * 32 + hl];
            a0 += (bflo(u0) + bflo(u1)) + (bflo(u2) + bflo(u3));
            a1 += (bfhi(u0) + bfhi(u1)) + (bfhi(u2) + bfhi(u3));
        }
        for (; j < nb; ++j) {
            int s = __shfl(sv, j, 32);
            unsigned int uu = h1s[(size_t)s * 32 + hl];
            a0 += bflo(uu);
            a1 += bfhi(uu);
        }
    }
    if (valid) {
        const float2 bb = *(const float2*)&b1[hl * 2];
        float v0 = fmaf(dn, a0, bb.x);
        float v1 = fmaf(dn, a1, bb.y);
        hrow[slot][hl * 2]     = v0 > 0.0f ? v0 : 0.0f;
        hrow[slot][hl * 2 + 1] = v1 > 0.0f ? v1 : 0.0f;
    }
    __syncthreads();
    // gemm2 epilogue: 20 active lanes per node, 2 cols each
    if (valid && hl < 20) {
        const int c2 = hl * 2;
        float s0 = 0.0f, s1 = 0.0f;
#pragma unroll 8
        for (int k = 0; k < D_HID; ++k) {
            float  xv = hrow[slot][k];
            float2 wv = *(const float2*)&w2s[k * D_OUT + c2];
            s0 = fmaf(xv, wv.x, s0);
            s1 = fmaf(xv, wv.y, s1);
        }
        unsigned int o = (unsigned)f2bf(s0 * dn) | ((unsigned)f2bf(s1 * dn) << 16);
        *(unsigned int*)&h2s[(size_t)node * D_OUT + c2] = o;
    }
}

// ---- gather2: out[n] = dinv[n]*(Σ h2s[s] + h2s[n]) + b2   [fp32 out] ----
__global__ __launch_bounds__(256) void k_gather2(const unsigned int* __restrict__ off,
                                                 const int* __restrict__ csr_src,
                                                 const unsigned int* __restrict__ h2s, // bf16x2
                                                 const float* __restrict__ dinv,
                                                 const float* __restrict__ b2,
                                                 float* __restrict__ out, int N) {
    const int gtid = blockIdx.x * 256 + threadIdx.x;
    const int wid2 = gtid >> 6;
    const int lane = threadIdx.x & 63;
    const int half = lane >> 5;
    const int hl   = lane & 31;
    const int node = wid2 * 2 + half;
    if (node >= N) return;
    const int start = (int)off[node];
    const int end   = (int)off[node + 1];
    const bool act = hl < 20;
    float a0 = 0.0f, a1 = 0.0f;
    if (act) {
        unsigned int u = h2s[(size_t)node * 20 + hl];
        a0 = bflo(u); a1 = bfhi(u);
    }
    for (int base = start; base < end; base += 32) {
        const int nb = min(32, end - base);
        int sv = (base + hl < end) ? csr_src[base + hl] : 0;
        int j = 0;
        for (; j + 3 < nb; j += 4) {
            int s0 = __shfl(sv, j, 32),     s1 = __shfl(sv, j + 1, 32);
            int s2 = __shfl(sv, j + 2, 32), s3 = __shfl(sv, j + 3, 32);
            if (act) {
                unsigned int u0 = h2s[(size_t)s0 * 20 + hl];
                unsigned int u1 = h2s[(size_t)s1 * 20 + hl];
                unsigned int u2 = h2s[(size_t)s2 * 20 + hl];
                unsigned int u3 = h2s[(size_t)s3 * 20 + hl];
                a0 += (bflo(u0) + bflo(u1)) + (bflo(u2) + bflo(u3));
                a1 += (bfhi(u0) + bfhi(u1)) + (bfhi(u2) + bfhi(u3));
            }
        }
        for (; j < nb; ++j) {
            int s = __shfl(sv, j, 32);
            if (act) {
                unsigned int uu = h2s[(size_t)s * 20 + hl];
                a0 += bflo(uu);
                a1 += bfhi(uu);
            }
        }
    }
    if (act) {
        const float dv = dinv[node];
        const float2 bb = *(const float2*)&b2[hl * 2];
        float2 o = {fmaf(dv, a0, bb.x), fmaf(dv, a1, bb.y)};
        *(float2*)&out[(size_t)node * D_OUT + hl * 2] = o;
    }
}

extern "C" void kernel_launch(void* const* d_in, const int* in_sizes, int n_in,
                              void* d_out, int out_size, void* d_ws, size_t ws_size,
                              hipStream_t stream) {
    const float* x  = (const float*)d_in[0];
    const int*  eix = (const int*)d_in[1];   // [2, E] int32 per harness contract
    const float* W1 = (const float*)d_in[2];
    const float* b1 = (const float*)d_in[3];
    const float* W2 = (const float*)d_in[4];
    const float* b2 = (const float*)d_in[5];
    float* out = (float*)d_out;

    const int N = in_sizes[0] / D_IN;
    const int E = in_sizes[1] / 2;
    const int* src = eix;
    const int* dst = eix + E;
    const int NB = (N + 255) / 256;   // scan blocks (<=512 required by k_scan2)

    // ws: deg | dinv | offsets(N+1) | bsums(512) | csr_src(E) | h1s(bf16) | h2s(bf16)
    // rank aliases h2s (rank dead after fill; h2s first written in k_g1g2, after fill).
    char* ws = (char*)d_ws;
    size_t off_b = 0;
    auto alloc = [&](size_t bytes) {
        void* p = ws + off_b;
        off_b = (off_b + bytes + 255) & ~(size_t)255;
        return p;
    };
    unsigned int*   deg     = (unsigned int*)alloc((size_t)N * 4);
    float*          dinv    = (float*)alloc((size_t)N * 4);
    unsigned int*   offsets = (unsigned int*)alloc((size_t)(N + 1) * 4);
    unsigned int*   bsums   = (unsigned int*)alloc(512 * 4);
    int*            csr_src = (int*)alloc((size_t)E * 4);
    unsigned short* h1s     = (unsigned short*)alloc((size_t)N * D_HID * 2);
    unsigned short* h2s     = (unsigned short*)alloc((size_t)E >= (size_t)N * D_OUT / 2
                                                     ? (size_t)E * 4 : (size_t)N * D_OUT * 2);
    unsigned int*   rank    = (unsigned int*)h2s;     // alias: rank dead before h2s written

    hipMemsetAsync(deg, 0, (size_t)N * 4, stream);

    // CSR build
    k_deg  <<<(E + 255) / 256, 256, 0, stream>>>(dst, deg, rank, E);
    k_scan1<<<NB, 256, 0, stream>>>(deg, offsets, bsums, dinv, N);
    k_scan2<<<1, 512, 0, stream>>>(bsums, NB);
    k_scan3<<<NB, 256, 0, stream>>>(offsets, bsums, N, E);

    // gemm1 (scaled h1s; depends on dinv) then fill
    k_gemm1<<<(N + 15) / 16, 256, 0, stream>>>(x, W1, dinv, h1s, N);
    k_fill <<<(E + 255) / 256, 256, 0, stream>>>(src, dst, offsets, rank, csr_src, E);

    // fused gather1 + gemm2 (8 nodes/block), then gather2
    k_g1g2  <<<(N + 7) / 8, 256, 0, stream>>>(offsets, csr_src, (const unsigned int*)h1s,
                                              dinv, b1, W2, h2s, N);
    const int gwaves = (N + 1) / 2;
    const int gblocks = (gwaves + 3) / 4;
    k_gather2<<<gblocks, 256, 0, stream>>>(offsets, csr_src, (const unsigned int*)h2s,
                                           dinv, b2, out, N);
}